// Round 5
// baseline (860.179 us; speedup 1.0000x reference)
//
#include <hip/hip_runtime.h>
#include <hip/hip_bf16.h>

typedef __hip_bfloat16 bf16;

struct Ptrs16 { const void* p[16]; };

// weight region element counts / offsets in the fp32 ws block (d_in[3..16])
__device__ __constant__ int wcnt[14] = {8192,64,8192,64,1024,64,64,4096,64,4096,64,1024,64,64};
__device__ __constant__ int woff[14] = {0,8192,8256,16448,16512,17536,17600,17664,21760,21824,25920,25984,27008,27072};
#define WTOTAL 27136

// ---------------------------------------------------------------------------
// Weight dtype detection. flags[b]=1 -> bf16, 0 -> fp32.
// ---------------------------------------------------------------------------
__global__ void detect_float(Ptrs16 ptrs, int n0, int n1, int* __restrict__ flags)
{
    int b = blockIdx.x, lane = threadIdx.x;
    int count = (b == 0) ? n0 : (b == 1) ? n1 : wcnt[b - 2];
    int limit = count < 1024 ? count : 1024;
    const unsigned short* us = (const unsigned short*)ptrs.p[b];
    int found = 0;
    for (int i = lane; i < limit; i += 64) {
        int e = (us[i] >> 7) & 0xFF;
        if (e >= 143) found = 1;
    }
    unsigned long long any = __ballot(found);
    if (lane == 0) flags[b] = (any != 0ull) ? 0 : 1;
}

__global__ void detect_idx(const int* __restrict__ ei, int* __restrict__ emode)
{
    if (threadIdx.x == 0) {
        int allz = 1;
        for (int i = 0; i < 128; i++)
            if (ei[2 * i + 1] != 0) { allz = 0; break; }
        emode[0] = allz;
    }
}

__global__ __launch_bounds__(256) void convert_weights(
    Ptrs16 ptrs, const int* __restrict__ flags, float* __restrict__ dst)
{
    int i = blockIdx.x * 256 + threadIdx.x;
    if (i >= WTOTAL) return;
    int r = 0;
    while (r < 13 && i >= woff[r + 1]) r++;
    int j = i - woff[r];
    const void* src = ptrs.p[2 + r];
    float v = flags[2 + r] ? __bfloat162float(((const bf16*)src)[j])
                           : ((const float*)src)[j];
    dst[i] = v;
}

// ---------------------------------------------------------------------------
// Degree count (int atomics only)
// ---------------------------------------------------------------------------
__global__ __launch_bounds__(256) void count_kernel(
    const int* __restrict__ ei, int* __restrict__ deg,
    const int* __restrict__ emode, int E, int N)
{
    int e = blockIdx.x * 256 + threadIdx.x;
    if (e >= E) return;
    int stride = 1 + emode[0];
    int d = ei[(E + e) * stride];
    if ((unsigned)d >= (unsigned)N) d = 0;
    atomicAdd(&deg[d], 1);
}

// ---------------------------------------------------------------------------
// Exclusive scan of deg -> rowptr
// ---------------------------------------------------------------------------
__global__ __launch_bounds__(256) void scan1(
    const int* __restrict__ deg, int* __restrict__ rowptr,
    int* __restrict__ bsum, int N)
{
    __shared__ int ts[256];
    int b = blockIdx.x, t = threadIdx.x;
    int base = b * 1024 + t * 4;
    int v[4]; int s = 0;
#pragma unroll
    for (int i = 0; i < 4; i++) {
        int idx = base + i;
        v[i] = (idx < N) ? deg[idx] : 0;
        s += v[i];
    }
    ts[t] = s;
    __syncthreads();
    for (int off = 1; off < 256; off <<= 1) {
        int x = (t >= off) ? ts[t - off] : 0;
        __syncthreads();
        ts[t] += x;
        __syncthreads();
    }
    int run = (t == 0) ? 0 : ts[t - 1];
#pragma unroll
    for (int i = 0; i < 4; i++) {
        run += v[i];
        int idx = base + i;
        if (idx < N) rowptr[idx + 1] = run;
    }
    if (t == 255) bsum[b] = ts[255];
}

__global__ __launch_bounds__(256) void scan2(int* __restrict__ bsum, int nb)
{
    __shared__ int s[256];
    int t = threadIdx.x;
    s[t] = (t < nb) ? bsum[t] : 0;
    __syncthreads();
    for (int off = 1; off < 256; off <<= 1) {
        int v = (t >= off) ? s[t - off] : 0;
        __syncthreads();
        s[t] += v;
        __syncthreads();
    }
    if (t < nb) bsum[t] = (t == 0) ? 0 : s[t - 1];
}

__global__ __launch_bounds__(256) void scan3(
    int* __restrict__ rowptr, int* __restrict__ fill,
    const int* __restrict__ bsum, int N)
{
    int i = blockIdx.x * 256 + threadIdx.x;
    if (i > N) return;
    int v = (i == 0) ? 0 : rowptr[i] + bsum[(i - 1) >> 10];
    rowptr[i] = v;
    if (i < N) fill[i] = v;
}

// ---------------------------------------------------------------------------
// Scatter edges into CSR order, FUSED with the edge-attr permute:
//   pos = fill[dst]++;  src_csr[pos] = src;  ea_csr[pos][0:16] = ea[e][0:16]
// ---------------------------------------------------------------------------
__global__ __launch_bounds__(256) void scatter_kernel(
    const int* __restrict__ ei, int* __restrict__ fill,
    const float* __restrict__ ea, float* __restrict__ ea_csr,
    int* __restrict__ src_csr, const int* __restrict__ emode, int E, int N)
{
    int e = blockIdx.x * 256 + threadIdx.x;
    if (e >= E) return;
    int stride = 1 + emode[0];
    int d = ei[(E + e) * stride];
    int s = ei[e * stride];
    if ((unsigned)d >= (unsigned)N) d = 0;
    if ((unsigned)s >= (unsigned)N) s = 0;
    const float4* ea4 = (const float4*)ea;
    float4 v0 = ea4[(long)e * 4 + 0];
    float4 v1 = ea4[(long)e * 4 + 1];
    float4 v2 = ea4[(long)e * 4 + 2];
    float4 v3 = ea4[(long)e * 4 + 3];
    int pos = atomicAdd(&fill[d], 1);
    src_csr[pos] = s;
    float4* dst = (float4*)ea_csr + (long)pos * 4;
    dst[0] = v0; dst[1] = v1; dst[2] = v2; dst[3] = v3;
}

// ---------------------------------------------------------------------------
// Node-feature GEMM: out{0,1}[N,64] = X[N,K] @ W{0,1}[K,64] + bias{0,1}
// ---------------------------------------------------------------------------
template<int K>
__global__ __launch_bounds__(256) void node_gemm(
    const float* __restrict__ X,
    const float* __restrict__ W0, const float* __restrict__ bias0, float* __restrict__ out0,
    const float* __restrict__ W1, const float* __restrict__ bias1, float* __restrict__ out1,
    int N)
{
    const float* W    = blockIdx.y ? W1 : W0;
    const float* bias = blockIdx.y ? bias1 : bias0;
    float* out        = blockIdx.y ? out1 : out0;

    __shared__ float Ws[K * 64];
    __shared__ float xs[4][4][K];

    for (int idx = threadIdx.x; idx < K * 64; idx += 256)
        Ws[idx] = W[idx];

    int wave = threadIdx.x >> 6, lane = threadIdx.x & 63;
    int r0 = blockIdx.x * 16 + wave * 4;
#pragma unroll
    for (int i = 0; i < 4; i++) {
        int r = r0 + i;
        for (int k = lane; k < K; k += 64)
            xs[wave][i][k] = (r < N) ? X[(long)r * K + k] : 0.0f;
    }
    __syncthreads();

    float a0 = 0.f, a1 = 0.f, a2 = 0.f, a3 = 0.f;
#pragma unroll 8
    for (int k = 0; k < K; k++) {
        float w = Ws[k * 64 + lane];
        a0 += xs[wave][0][k] * w;
        a1 += xs[wave][1][k] * w;
        a2 += xs[wave][2][k] * w;
        a3 += xs[wave][3][k] * w;
    }
    float bz = bias[lane];
    if (r0 + 0 < N) out[(long)(r0 + 0) * 64 + lane] = a0 + bz;
    if (r0 + 1 < N) out[(long)(r0 + 1) * 64 + lane] = a1 + bz;
    if (r0 + 2 < N) out[(long)(r0 + 2) * 64 + lane] = a2 + bz;
    if (r0 + 3 < N) out[(long)(r0 + 3) * 64 + lane] = a3 + bz;
}

// ---------------------------------------------------------------------------
// DPP add helper: t += t[permuted lane] as a pure-VALU op (~4cy vs ~120cy for
// a ds_bpermute shuffle). ctrl must be a literal.
//   quad_perm xor1 = 0xB1 ([1,0,3,2]);  quad_perm xor2 = 0x4E ([2,3,0,1])
//   row_shr:N = 0x110+N;  row_bcast:15 = 0x142;  row_bcast:31 = 0x143
// ---------------------------------------------------------------------------
#define DPP_ADD(t, ctrl)                                                      \
    t += __int_as_float(__builtin_amdgcn_update_dpp(                          \
             0, __float_as_int(t), (ctrl), 0xF, 0xF, true))

// group-sum of t over CPH-lane groups, result valid in every lane.
template<int CPH>
__device__ __forceinline__ float group_reduce(float t)
{
    if (CPH == 8) {
        DPP_ADD(t, 0xB1);                 // + lane^1   (quad_perm, VALU)
        DPP_ADD(t, 0x4E);                 // + lane^2   (quad_perm, VALU)
        t += __shfl_xor(t, 4, 64);        // + lane^4   (only DS op)
    } else {
        // classic GCN wave64 reduce: 6 DPP adds + readlane, zero DS ops
        DPP_ADD(t, 0x111);                // row_shr:1
        DPP_ADD(t, 0x112);                // row_shr:2
        DPP_ADD(t, 0x114);                // row_shr:4
        DPP_ADD(t, 0x118);                // row_shr:8  -> lane15 of each row16 = row sum
        DPP_ADD(t, 0x142);                // row_bcast:15 -> lane31 = sum(0..31), lane63 = sum(32..63)
        DPP_ADD(t, 0x143);                // row_bcast:31 -> lane63 = sum(0..63)
        t = __int_as_float(__builtin_amdgcn_readlane(__float_as_int(t), 63));
    }
    return t;
}

// ---------------------------------------------------------------------------
// GATv2 aggregation v10: wave per dst node, lane = channel.
//  v9 -> v10 (xl gather latency attack; issue-slot arithmetic showed ~31%
//  VALU issue utilization -> still latency-bound; FETCH 267MB says part of
//  the xl gathers miss L3 to HBM ~900cy; 8-deep cover was only ~640cy):
//  - xl rolling pipeline deepened 8 -> 16 named slots; refill distance +16
//    aligns slot I with the same position in the next 16-edge LDS chunk.
//    Cover ~16 bodies ~1280cy > s_load(src)+HBM(xl) chain. +8 VGPR only.
//  - everything else identical to v9 (DPP reduce, LDS ea staging, numerics
//    preserved: same even/odd accumulator parity, same add order)
// ---------------------------------------------------------------------------
template<int CPH, bool FINAL>
__global__ __launch_bounds__(256) void edge_kernel(
    const int* __restrict__ rowptr, const int* __restrict__ src_csr,
    const float* __restrict__ ea_csr,
    const float* __restrict__ xl, const float* __restrict__ xr,
    const float* __restrict__ We, const float* __restrict__ att,
    const float* __restrict__ bias, float* __restrict__ outp, int N)
{
    __shared__ float elds[4][256];          // per-wave 1KB chunk buffer

    int lane = threadIdx.x & 63;
    int wave = __builtin_amdgcn_readfirstlane(threadIdx.x >> 6);
    int n = blockIdx.x * 4 + wave;
    if (n >= N) return;                     // no barriers below: safe

    float wcol[16];
#pragma unroll
    for (int k = 0; k < 16; k++) wcol[k] = We[k * 64 + lane];
    float attc = att[lane];
    float xrc  = xr[(unsigned)n * 64 + lane];

    int p0 = __builtin_amdgcn_readfirstlane(rowptr[n]);
    int p1 = __builtin_amdgcn_readfirstlane(rowptr[n + 1]);
    int deg = p1 - p0;

    float l0 = 0.f, acc0 = 0.f, ees0 = 0.f;
    float l1 = 0.f, acc1 = 0.f, ees1 = 0.f;

#define BODY(I, XS, LL, AC, EE_) do {                                        \
    if (cbase + (I) < p1) {                                                  \
        const float4* ep_ = (const float4*)(lb + (I) * 16);                  \
        float4 a0 = ep_[0], a1 = ep_[1], a2 = ep_[2], a3 = ep_[3];           \
        float xls = XS;                                                      \
        int pn_ = cbase + (I) + 16; pn_ = (pn_ <= pl) ? pn_ : pl;            \
        int sn_ = __builtin_amdgcn_readfirstlane(src_csr[pn_]);              \
        XS = xl[(unsigned)sn_ * 64 + lane];                                  \
        float t0 = a0.x*wcol[0]  + a0.y*wcol[1];                             \
        float t1 = a0.z*wcol[2]  + a0.w*wcol[3];                             \
        float t2 = a1.x*wcol[4]  + a1.y*wcol[5];                             \
        float t3 = a1.z*wcol[6]  + a1.w*wcol[7];                             \
        float t4 = a2.x*wcol[8]  + a2.y*wcol[9];                             \
        float t5 = a2.z*wcol[10] + a2.w*wcol[11];                            \
        float t6 = a3.x*wcol[12] + a3.y*wcol[13];                            \
        float t7 = a3.z*wcol[14] + a3.w*wcol[15];                            \
        float ee = ((t0 + t1) + (t2 + t3)) + ((t4 + t5) + (t6 + t7));        \
        EE_ += ee;                                                           \
        float z = xls + xrc + ee;                                            \
        z = (z > 0.f) ? z : 0.2f * z;                                        \
        float t = group_reduce<CPH>(z * attc);                               \
        float pe = __expf(t);                                                \
        LL += pe; AC += pe * xls;                                            \
    } } while (0)

    if (deg > 0) {
        const float4* ea4c = (const float4*)ea_csr;
        float* lb = &elds[wave][0];
        int pl = p1 - 1;

        // prefetch chunk 0 (ea) + xl slots for edges p0..p0+15 (clamped)
        float4 nxt = ea4c[(long)p0 * 4 + lane];
#define CLAMP_IDX(K_) ((p0 + (K_) <= pl) ? p0 + (K_) : pl)
        int s0  = __builtin_amdgcn_readfirstlane(src_csr[p0]);
        int s1  = __builtin_amdgcn_readfirstlane(src_csr[CLAMP_IDX(1)]);
        int s2  = __builtin_amdgcn_readfirstlane(src_csr[CLAMP_IDX(2)]);
        int s3  = __builtin_amdgcn_readfirstlane(src_csr[CLAMP_IDX(3)]);
        int s4  = __builtin_amdgcn_readfirstlane(src_csr[CLAMP_IDX(4)]);
        int s5  = __builtin_amdgcn_readfirstlane(src_csr[CLAMP_IDX(5)]);
        int s6  = __builtin_amdgcn_readfirstlane(src_csr[CLAMP_IDX(6)]);
        int s7  = __builtin_amdgcn_readfirstlane(src_csr[CLAMP_IDX(7)]);
        int s8  = __builtin_amdgcn_readfirstlane(src_csr[CLAMP_IDX(8)]);
        int s9  = __builtin_amdgcn_readfirstlane(src_csr[CLAMP_IDX(9)]);
        int s10 = __builtin_amdgcn_readfirstlane(src_csr[CLAMP_IDX(10)]);
        int s11 = __builtin_amdgcn_readfirstlane(src_csr[CLAMP_IDX(11)]);
        int s12 = __builtin_amdgcn_readfirstlane(src_csr[CLAMP_IDX(12)]);
        int s13 = __builtin_amdgcn_readfirstlane(src_csr[CLAMP_IDX(13)]);
        int s14 = __builtin_amdgcn_readfirstlane(src_csr[CLAMP_IDX(14)]);
        int s15 = __builtin_amdgcn_readfirstlane(src_csr[CLAMP_IDX(15)]);
#undef CLAMP_IDX
        float x0  = xl[(unsigned)s0  * 64 + lane];
        float x1  = xl[(unsigned)s1  * 64 + lane];
        float x2  = xl[(unsigned)s2  * 64 + lane];
        float x3  = xl[(unsigned)s3  * 64 + lane];
        float x4  = xl[(unsigned)s4  * 64 + lane];
        float x5  = xl[(unsigned)s5  * 64 + lane];
        float x6  = xl[(unsigned)s6  * 64 + lane];
        float x7  = xl[(unsigned)s7  * 64 + lane];
        float x8  = xl[(unsigned)s8  * 64 + lane];
        float x9  = xl[(unsigned)s9  * 64 + lane];
        float x10 = xl[(unsigned)s10 * 64 + lane];
        float x11 = xl[(unsigned)s11 * 64 + lane];
        float x12 = xl[(unsigned)s12 * 64 + lane];
        float x13 = xl[(unsigned)s13 * 64 + lane];
        float x14 = xl[(unsigned)s14 * 64 + lane];
        float x15 = xl[(unsigned)s15 * 64 + lane];

        int nch = (deg + 15) >> 4;
        for (int ch = 0; ch < nch; ch++) {
            int cbase = p0 + (ch << 4);
            ((float4*)lb)[lane] = nxt;               // LDS fill (in-order DS pipe)
            if (ch + 1 < nch)
                nxt = ea4c[(long)(cbase + 16) * 4 + lane];
            BODY(0,  x0,  l0, acc0, ees0);
            BODY(1,  x1,  l1, acc1, ees1);
            BODY(2,  x2,  l0, acc0, ees0);
            BODY(3,  x3,  l1, acc1, ees1);
            BODY(4,  x4,  l0, acc0, ees0);
            BODY(5,  x5,  l1, acc1, ees1);
            BODY(6,  x6,  l0, acc0, ees0);
            BODY(7,  x7,  l1, acc1, ees1);
            BODY(8,  x8,  l0, acc0, ees0);
            BODY(9,  x9,  l1, acc1, ees1);
            BODY(10, x10, l0, acc0, ees0);
            BODY(11, x11, l1, acc1, ees1);
            BODY(12, x12, l0, acc0, ees0);
            BODY(13, x13, l1, acc1, ees1);
            BODY(14, x14, l0, acc0, ees0);
            BODY(15, x15, l1, acc1, ees1);
        }
    }
#undef BODY

    float l = l0 + l1, acc = acc0 + acc1, eeacc = ees0 + ees1;

    // self-loop: edge_attr = mean of incoming => ee_self = eeacc/deg (linear)
    {
        float eeS = (deg > 0) ? eeacc / (float)deg : 0.f;
        float xls = xl[(unsigned)n * 64 + lane];
        float z = xls + xrc + eeS;
        z = (z > 0.f) ? z : 0.2f * z;
        float t = group_reduce<CPH>(z * attc);
        float pe = __expf(t);
        l   += pe;
        acc += pe * xls;
    }

    float out = acc / (l + 1e-16f);
    float v = out + bias[lane];
    if (FINAL) {
        outp[(unsigned)n * 64 + lane] = v;
    } else {
        outp[(unsigned)n * 64 + lane] = (v > 0.f) ? v : (__expf(v) - 1.f);   // ELU
    }
}

// ---------------------------------------------------------------------------
extern "C" void kernel_launch(void* const* d_in, const int* in_sizes, int n_in,
                              void* d_out, int out_size, void* d_ws, size_t ws_size,
                              hipStream_t stream)
{
    const int N = in_sizes[0] / 128;
    const int E = (in_sizes[1] >= 6000000) ? in_sizes[1] / 4 : in_sizes[1] / 2;

    const int*   ei = (const int*)  d_in[1];
    const float* x  = (const float*)d_in[0];
    const float* ea = (const float*)d_in[2];

    Ptrs16 ptrs;
    ptrs.p[0] = d_in[0];
    ptrs.p[1] = d_in[2];
    for (int i = 0; i < 14; i++) ptrs.p[2 + i] = d_in[3 + i];

    char* p = (char*)d_ws;
    auto carve = [&](size_t bytes) {
        char* r = p;
        p += (bytes + 255) & ~(size_t)255;
        return r;
    };
    int*   flags   = (int*)  carve(256);
    int*   emode   = (int*)  carve(256);
    float* wts     = (float*)carve((size_t)WTOTAL * 4);
    int*   deg     = (int*)  carve((size_t)N * 4);
    int*   rowptr  = (int*)  carve((size_t)(N + 1) * 4);
    int*   fill    = (int*)  carve((size_t)N * 4);
    int*   bsum    = (int*)  carve(1024);
    float* xl      = (float*)carve((size_t)N * 64 * 4);
    float* xr      = (float*)carve((size_t)N * 64 * 4);
    float* h       = (float*)carve((size_t)N * 64 * 4);
    float* ea_csr  = (float*)carve((size_t)(E + 32) * 16 * 4);  // +32 rows pad
    int*   src_csr = (int*)  carve((size_t)(E + 32) * 4);
    (void)ws_size; (void)n_in; (void)out_size;

    const float* Wl1f  = wts + 0;     const float* bl1f = wts + 8192;
    const float* Wr1f  = wts + 8256;  const float* br1f = wts + 16448;
    const float* We1f  = wts + 16512; const float* att1f= wts + 17536;
    const float* b1f   = wts + 17600;
    const float* Wl2f  = wts + 17664; const float* bl2f = wts + 21760;
    const float* Wr2f  = wts + 21824; const float* br2f = wts + 25920;
    const float* We2f  = wts + 25984; const float* att2f= wts + 27008;
    const float* b2f   = wts + 27072;

    hipMemsetAsync(deg, 0, (size_t)N * 4, stream);

    detect_float<<<16, 64, 0, stream>>>(ptrs, in_sizes[0], in_sizes[2], flags);
    detect_idx<<<1, 64, 0, stream>>>(ei, emode);
    convert_weights<<<(WTOTAL + 255) / 256, 256, 0, stream>>>(ptrs, flags, wts);

    count_kernel<<<(E + 255) / 256, 256, 0, stream>>>(ei, deg, emode, E, N);

    int nb = (N + 1023) / 1024;
    scan1<<<nb, 256, 0, stream>>>(deg, rowptr, bsum, N);
    scan2<<<1, 256, 0, stream>>>(bsum, nb);
    scan3<<<(N + 256) / 256, 256, 0, stream>>>(rowptr, fill, bsum, N);

    // scatter + ea permute fused (no intermediate edges array / ea_gather)
    scatter_kernel<<<(E + 255) / 256, 256, 0, stream>>>(
        ei, fill, ea, ea_csr, src_csr, emode, E, N);

    // Layer 1
    dim3 g1((N + 15) / 16, 2);
    node_gemm<128><<<g1, 256, 0, stream>>>(x, Wl1f, bl1f, xl, Wr1f, br1f, xr, N);
    int ng = (N + 3) / 4;
    edge_kernel<8, false><<<ng, 256, 0, stream>>>(
        rowptr, src_csr, ea_csr, xl, xr, We1f, att1f, b1f, h, N);

    // Layer 2
    node_gemm<64><<<g1, 256, 0, stream>>>(h, Wl2f, bl2f, xl, Wr2f, br2f, xr, N);
    edge_kernel<64, true><<<ng, 256, 0, stream>>>(
        rowptr, src_csr, ea_csr, xl, xr, We2f, att2f, b2f, (float*)d_out, N);
}

// Round 6
// 832.718 us; speedup vs baseline: 1.0330x; 1.0330x over previous
//
#include <hip/hip_runtime.h>
#include <hip/hip_bf16.h>

typedef __hip_bfloat16 bf16;

struct Ptrs16 { const void* p[16]; };

// weight region element counts / offsets in the fp32 ws block (d_in[3..16])
__device__ __constant__ int wcnt[14] = {8192,64,8192,64,1024,64,64,4096,64,4096,64,1024,64,64};
__device__ __constant__ int woff[14] = {0,8192,8256,16448,16512,17536,17600,17664,21760,21824,25920,25984,27008,27072};
#define WTOTAL 27136

// ---------------------------------------------------------------------------
// Weight dtype detection. flags[b]=1 -> bf16, 0 -> fp32.
// ---------------------------------------------------------------------------
__global__ void detect_float(Ptrs16 ptrs, int n0, int n1, int* __restrict__ flags)
{
    int b = blockIdx.x, lane = threadIdx.x;
    int count = (b == 0) ? n0 : (b == 1) ? n1 : wcnt[b - 2];
    int limit = count < 1024 ? count : 1024;
    const unsigned short* us = (const unsigned short*)ptrs.p[b];
    int found = 0;
    for (int i = lane; i < limit; i += 64) {
        int e = (us[i] >> 7) & 0xFF;
        if (e >= 143) found = 1;
    }
    unsigned long long any = __ballot(found);
    if (lane == 0) flags[b] = (any != 0ull) ? 0 : 1;
}

__global__ void detect_idx(const int* __restrict__ ei, int* __restrict__ emode)
{
    if (threadIdx.x == 0) {
        int allz = 1;
        for (int i = 0; i < 128; i++)
            if (ei[2 * i + 1] != 0) { allz = 0; break; }
        emode[0] = allz;
    }
}

__global__ __launch_bounds__(256) void convert_weights(
    Ptrs16 ptrs, const int* __restrict__ flags, float* __restrict__ dst)
{
    int i = blockIdx.x * 256 + threadIdx.x;
    if (i >= WTOTAL) return;
    int r = 0;
    while (r < 13 && i >= woff[r + 1]) r++;
    int j = i - woff[r];
    const void* src = ptrs.p[2 + r];
    float v = flags[2 + r] ? __bfloat162float(((const bf16*)src)[j])
                           : ((const float*)src)[j];
    dst[i] = v;
}

// ---------------------------------------------------------------------------
// Degree count (int atomics only)
// ---------------------------------------------------------------------------
__global__ __launch_bounds__(256) void count_kernel(
    const int* __restrict__ ei, int* __restrict__ deg,
    const int* __restrict__ emode, int E, int N)
{
    int e = blockIdx.x * 256 + threadIdx.x;
    if (e >= E) return;
    int stride = 1 + emode[0];
    int d = ei[(E + e) * stride];
    if ((unsigned)d >= (unsigned)N) d = 0;
    atomicAdd(&deg[d], 1);
}

// ---------------------------------------------------------------------------
// Exclusive scan of deg -> rowptr
// ---------------------------------------------------------------------------
__global__ __launch_bounds__(256) void scan1(
    const int* __restrict__ deg, int* __restrict__ rowptr,
    int* __restrict__ bsum, int N)
{
    __shared__ int ts[256];
    int b = blockIdx.x, t = threadIdx.x;
    int base = b * 1024 + t * 4;
    int v[4]; int s = 0;
#pragma unroll
    for (int i = 0; i < 4; i++) {
        int idx = base + i;
        v[i] = (idx < N) ? deg[idx] : 0;
        s += v[i];
    }
    ts[t] = s;
    __syncthreads();
    for (int off = 1; off < 256; off <<= 1) {
        int x = (t >= off) ? ts[t - off] : 0;
        __syncthreads();
        ts[t] += x;
        __syncthreads();
    }
    int run = (t == 0) ? 0 : ts[t - 1];
#pragma unroll
    for (int i = 0; i < 4; i++) {
        run += v[i];
        int idx = base + i;
        if (idx < N) rowptr[idx + 1] = run;
    }
    if (t == 255) bsum[b] = ts[255];
}

__global__ __launch_bounds__(256) void scan2(int* __restrict__ bsum, int nb)
{
    __shared__ int s[256];
    int t = threadIdx.x;
    s[t] = (t < nb) ? bsum[t] : 0;
    __syncthreads();
    for (int off = 1; off < 256; off <<= 1) {
        int v = (t >= off) ? s[t - off] : 0;
        __syncthreads();
        s[t] += v;
        __syncthreads();
    }
    if (t < nb) bsum[t] = (t == 0) ? 0 : s[t - 1];
}

__global__ __launch_bounds__(256) void scan3(
    int* __restrict__ rowptr, int* __restrict__ fill,
    const int* __restrict__ bsum, int N)
{
    int i = blockIdx.x * 256 + threadIdx.x;
    if (i > N) return;
    int v = (i == 0) ? 0 : rowptr[i] + bsum[(i - 1) >> 10];
    rowptr[i] = v;
    if (i < N) fill[i] = v;
}

// ---------------------------------------------------------------------------
// Scatter edges into CSR order, FUSED with the edge-attr permute:
//   pos = fill[dst]++;  src_csr[pos] = src;  ea_csr[pos][0:16] = ea[e][0:16]
// ---------------------------------------------------------------------------
__global__ __launch_bounds__(256) void scatter_kernel(
    const int* __restrict__ ei, int* __restrict__ fill,
    const float* __restrict__ ea, float* __restrict__ ea_csr,
    int* __restrict__ src_csr, const int* __restrict__ emode, int E, int N)
{
    int e = blockIdx.x * 256 + threadIdx.x;
    if (e >= E) return;
    int stride = 1 + emode[0];
    int d = ei[(E + e) * stride];
    int s = ei[e * stride];
    if ((unsigned)d >= (unsigned)N) d = 0;
    if ((unsigned)s >= (unsigned)N) s = 0;
    const float4* ea4 = (const float4*)ea;
    float4 v0 = ea4[(long)e * 4 + 0];
    float4 v1 = ea4[(long)e * 4 + 1];
    float4 v2 = ea4[(long)e * 4 + 2];
    float4 v3 = ea4[(long)e * 4 + 3];
    int pos = atomicAdd(&fill[d], 1);
    src_csr[pos] = s;
    float4* dst = (float4*)ea_csr + (long)pos * 4;
    dst[0] = v0; dst[1] = v1; dst[2] = v2; dst[3] = v3;
}

// ---------------------------------------------------------------------------
// Node-feature GEMM: out{0,1}[N,64] = X[N,K] @ W{0,1}[K,64] + bias{0,1}
//  v2: k-loop unrolled by 4; xs row values read as ONE broadcast ds_read_b128
//  per row per 4 k (was 4 broadcast b32 per k). DS ops per 4k: 20 -> 8.
//  The old version was DS-issue-bound (5 ds_read per k vs 4 FMA).
// ---------------------------------------------------------------------------
template<int K>
__global__ __launch_bounds__(256) void node_gemm(
    const float* __restrict__ X,
    const float* __restrict__ W0, const float* __restrict__ bias0, float* __restrict__ out0,
    const float* __restrict__ W1, const float* __restrict__ bias1, float* __restrict__ out1,
    int N)
{
    const float* W    = blockIdx.y ? W1 : W0;
    const float* bias = blockIdx.y ? bias1 : bias0;
    float* out        = blockIdx.y ? out1 : out0;

    __shared__ float Ws[K * 64];
    __shared__ float xs[4][4][K];

    for (int idx = threadIdx.x; idx < K * 64; idx += 256)
        Ws[idx] = W[idx];

    int wave = threadIdx.x >> 6, lane = threadIdx.x & 63;
    int r0 = blockIdx.x * 16 + wave * 4;
#pragma unroll
    for (int i = 0; i < 4; i++) {
        int r = r0 + i;
        for (int k = lane; k < K; k += 64)
            xs[wave][i][k] = (r < N) ? X[(long)r * K + k] : 0.0f;
    }
    __syncthreads();

    float a0 = 0.f, a1 = 0.f, a2 = 0.f, a3 = 0.f;
#pragma unroll 4
    for (int k = 0; k < K; k += 4) {
        float4 xv0 = *(const float4*)&xs[wave][0][k];
        float4 xv1 = *(const float4*)&xs[wave][1][k];
        float4 xv2 = *(const float4*)&xs[wave][2][k];
        float4 xv3 = *(const float4*)&xs[wave][3][k];
        float w0 = Ws[(k + 0) * 64 + lane];
        float w1 = Ws[(k + 1) * 64 + lane];
        float w2 = Ws[(k + 2) * 64 + lane];
        float w3 = Ws[(k + 3) * 64 + lane];
        a0 += xv0.x * w0; a1 += xv1.x * w0; a2 += xv2.x * w0; a3 += xv3.x * w0;
        a0 += xv0.y * w1; a1 += xv1.y * w1; a2 += xv2.y * w1; a3 += xv3.y * w1;
        a0 += xv0.z * w2; a1 += xv1.z * w2; a2 += xv2.z * w2; a3 += xv3.z * w2;
        a0 += xv0.w * w3; a1 += xv1.w * w3; a2 += xv2.w * w3; a3 += xv3.w * w3;
    }
    float bz = bias[lane];
    if (r0 + 0 < N) out[(long)(r0 + 0) * 64 + lane] = a0 + bz;
    if (r0 + 1 < N) out[(long)(r0 + 1) * 64 + lane] = a1 + bz;
    if (r0 + 2 < N) out[(long)(r0 + 2) * 64 + lane] = a2 + bz;
    if (r0 + 3 < N) out[(long)(r0 + 3) * 64 + lane] = a3 + bz;
}

// ---------------------------------------------------------------------------
// DPP add helper: t += t[permuted lane] as a pure-VALU op (~4cy vs ~120cy for
// a ds_bpermute shuffle). ctrl must be a literal.
//   quad_perm xor1 = 0xB1 ([1,0,3,2]);  quad_perm xor2 = 0x4E ([2,3,0,1])
//   row_shr:N = 0x110+N;  row_bcast:15 = 0x142;  row_bcast:31 = 0x143
// ---------------------------------------------------------------------------
#define DPP_ADD(t, ctrl)                                                      \
    t += __int_as_float(__builtin_amdgcn_update_dpp(                          \
             0, __float_as_int(t), (ctrl), 0xF, 0xF, true))

// group-sum of t over CPH-lane groups, result valid in every lane.
template<int CPH>
__device__ __forceinline__ float group_reduce(float t)
{
    if (CPH == 8) {
        DPP_ADD(t, 0xB1);                 // + lane^1   (quad_perm, VALU)
        DPP_ADD(t, 0x4E);                 // + lane^2   (quad_perm, VALU)
        t += __shfl_xor(t, 4, 64);        // + lane^4   (only DS op)
    } else {
        // classic GCN wave64 reduce: 6 DPP adds + readlane, zero DS ops
        DPP_ADD(t, 0x111);                // row_shr:1
        DPP_ADD(t, 0x112);                // row_shr:2
        DPP_ADD(t, 0x114);                // row_shr:4
        DPP_ADD(t, 0x118);                // row_shr:8  -> lane15 of each row16 = row sum
        DPP_ADD(t, 0x142);                // row_bcast:15 -> lane31 = sum(0..31), lane63 = sum(32..63)
        DPP_ADD(t, 0x143);                // row_bcast:31 -> lane63 = sum(0..63)
        t = __int_as_float(__builtin_amdgcn_readlane(__float_as_int(t), 63));
    }
    return t;
}

// ---------------------------------------------------------------------------
// GATv2 aggregation v9 (REVERTED from v10: depth-16 cost occupancy 55->48%
// and wasted prefetch on short rows; measured 179.5us vs 209.7us).
//  wave per dst node, lane = channel.
//  - shuffle-reduce chains replaced by DPP adds (VALU)
//  - xl rolling prefetch pipeline: 8 named slots, refill distance +8
//  - ea via per-wave LDS chunk staging, one 16-edge chunk ahead
//  - self-loop folded via linearity: ee_self = sum(ee)/deg
// ---------------------------------------------------------------------------
template<int CPH, bool FINAL>
__global__ __launch_bounds__(256) void edge_kernel(
    const int* __restrict__ rowptr, const int* __restrict__ src_csr,
    const float* __restrict__ ea_csr,
    const float* __restrict__ xl, const float* __restrict__ xr,
    const float* __restrict__ We, const float* __restrict__ att,
    const float* __restrict__ bias, float* __restrict__ outp, int N)
{
    __shared__ float elds[4][256];          // per-wave 1KB chunk buffer

    int lane = threadIdx.x & 63;
    int wave = __builtin_amdgcn_readfirstlane(threadIdx.x >> 6);
    int n = blockIdx.x * 4 + wave;
    if (n >= N) return;                     // no barriers below: safe

    float wcol[16];
#pragma unroll
    for (int k = 0; k < 16; k++) wcol[k] = We[k * 64 + lane];
    float attc = att[lane];
    float xrc  = xr[(unsigned)n * 64 + lane];

    int p0 = __builtin_amdgcn_readfirstlane(rowptr[n]);
    int p1 = __builtin_amdgcn_readfirstlane(rowptr[n + 1]);
    int deg = p1 - p0;

    float l0 = 0.f, acc0 = 0.f, ees0 = 0.f;
    float l1 = 0.f, acc1 = 0.f, ees1 = 0.f;

#define BODY(I, XS, LL, AC, EE_) do {                                        \
    if (cbase + (I) < p1) {                                                  \
        const float4* ep_ = (const float4*)(lb + (I) * 16);                  \
        float4 a0 = ep_[0], a1 = ep_[1], a2 = ep_[2], a3 = ep_[3];           \
        float xls = XS;                                                      \
        int pn_ = cbase + (I) + 8; pn_ = (pn_ <= pl) ? pn_ : pl;             \
        int sn_ = __builtin_amdgcn_readfirstlane(src_csr[pn_]);              \
        XS = xl[(unsigned)sn_ * 64 + lane];                                  \
        float t0 = a0.x*wcol[0]  + a0.y*wcol[1];                             \
        float t1 = a0.z*wcol[2]  + a0.w*wcol[3];                             \
        float t2 = a1.x*wcol[4]  + a1.y*wcol[5];                             \
        float t3 = a1.z*wcol[6]  + a1.w*wcol[7];                             \
        float t4 = a2.x*wcol[8]  + a2.y*wcol[9];                             \
        float t5 = a2.z*wcol[10] + a2.w*wcol[11];                            \
        float t6 = a3.x*wcol[12] + a3.y*wcol[13];                            \
        float t7 = a3.z*wcol[14] + a3.w*wcol[15];                            \
        float ee = ((t0 + t1) + (t2 + t3)) + ((t4 + t5) + (t6 + t7));        \
        EE_ += ee;                                                           \
        float z = xls + xrc + ee;                                            \
        z = (z > 0.f) ? z : 0.2f * z;                                        \
        float t = group_reduce<CPH>(z * attc);                               \
        float pe = __expf(t);                                                \
        LL += pe; AC += pe * xls;                                            \
    } } while (0)

    if (deg > 0) {
        const float4* ea4c = (const float4*)ea_csr;
        float* lb = &elds[wave][0];
        int pl = p1 - 1;

        // prefetch chunk 0 (ea) + xl slots for edges p0..p0+7 (clamped)
        float4 nxt = ea4c[(long)p0 * 4 + lane];
        int i1 = (p0 + 1 <= pl) ? p0 + 1 : pl;
        int i2 = (p0 + 2 <= pl) ? p0 + 2 : pl;
        int i3 = (p0 + 3 <= pl) ? p0 + 3 : pl;
        int i4 = (p0 + 4 <= pl) ? p0 + 4 : pl;
        int i5 = (p0 + 5 <= pl) ? p0 + 5 : pl;
        int i6 = (p0 + 6 <= pl) ? p0 + 6 : pl;
        int i7 = (p0 + 7 <= pl) ? p0 + 7 : pl;
        int s0 = __builtin_amdgcn_readfirstlane(src_csr[p0]);
        int s1 = __builtin_amdgcn_readfirstlane(src_csr[i1]);
        int s2 = __builtin_amdgcn_readfirstlane(src_csr[i2]);
        int s3 = __builtin_amdgcn_readfirstlane(src_csr[i3]);
        int s4 = __builtin_amdgcn_readfirstlane(src_csr[i4]);
        int s5 = __builtin_amdgcn_readfirstlane(src_csr[i5]);
        int s6 = __builtin_amdgcn_readfirstlane(src_csr[i6]);
        int s7 = __builtin_amdgcn_readfirstlane(src_csr[i7]);
        float x0 = xl[(unsigned)s0 * 64 + lane];
        float x1 = xl[(unsigned)s1 * 64 + lane];
        float x2 = xl[(unsigned)s2 * 64 + lane];
        float x3 = xl[(unsigned)s3 * 64 + lane];
        float x4 = xl[(unsigned)s4 * 64 + lane];
        float x5 = xl[(unsigned)s5 * 64 + lane];
        float x6 = xl[(unsigned)s6 * 64 + lane];
        float x7 = xl[(unsigned)s7 * 64 + lane];

        int nch = (deg + 15) >> 4;
        for (int ch = 0; ch < nch; ch++) {
            int cbase = p0 + (ch << 4);
            ((float4*)lb)[lane] = nxt;               // LDS fill (in-order DS pipe)
            if (ch + 1 < nch)
                nxt = ea4c[(long)(cbase + 16) * 4 + lane];
#pragma unroll
            for (int g = 0; g < 2; g++) {
                BODY(g * 8 + 0, x0, l0, acc0, ees0);
                BODY(g * 8 + 1, x1, l1, acc1, ees1);
                BODY(g * 8 + 2, x2, l0, acc0, ees0);
                BODY(g * 8 + 3, x3, l1, acc1, ees1);
                BODY(g * 8 + 4, x4, l0, acc0, ees0);
                BODY(g * 8 + 5, x5, l1, acc1, ees1);
                BODY(g * 8 + 6, x6, l0, acc0, ees0);
                BODY(g * 8 + 7, x7, l1, acc1, ees1);
            }
        }
    }
#undef BODY

    float l = l0 + l1, acc = acc0 + acc1, eeacc = ees0 + ees1;

    // self-loop: edge_attr = mean of incoming => ee_self = eeacc/deg (linear)
    {
        float eeS = (deg > 0) ? eeacc / (float)deg : 0.f;
        float xls = xl[(unsigned)n * 64 + lane];
        float z = xls + xrc + eeS;
        z = (z > 0.f) ? z : 0.2f * z;
        float t = group_reduce<CPH>(z * attc);
        float pe = __expf(t);
        l   += pe;
        acc += pe * xls;
    }

    float out = acc / (l + 1e-16f);
    float v = out + bias[lane];
    if (FINAL) {
        outp[(unsigned)n * 64 + lane] = v;
    } else {
        outp[(unsigned)n * 64 + lane] = (v > 0.f) ? v : (__expf(v) - 1.f);   // ELU
    }
}

// ---------------------------------------------------------------------------
extern "C" void kernel_launch(void* const* d_in, const int* in_sizes, int n_in,
                              void* d_out, int out_size, void* d_ws, size_t ws_size,
                              hipStream_t stream)
{
    const int N = in_sizes[0] / 128;
    const int E = (in_sizes[1] >= 6000000) ? in_sizes[1] / 4 : in_sizes[1] / 2;

    const int*   ei = (const int*)  d_in[1];
    const float* x  = (const float*)d_in[0];
    const float* ea = (const float*)d_in[2];

    Ptrs16 ptrs;
    ptrs.p[0] = d_in[0];
    ptrs.p[1] = d_in[2];
    for (int i = 0; i < 14; i++) ptrs.p[2 + i] = d_in[3 + i];

    char* p = (char*)d_ws;
    auto carve = [&](size_t bytes) {
        char* r = p;
        p += (bytes + 255) & ~(size_t)255;
        return r;
    };
    int*   flags   = (int*)  carve(256);
    int*   emode   = (int*)  carve(256);
    float* wts     = (float*)carve((size_t)WTOTAL * 4);
    int*   deg     = (int*)  carve((size_t)N * 4);
    int*   rowptr  = (int*)  carve((size_t)(N + 1) * 4);
    int*   fill    = (int*)  carve((size_t)N * 4);
    int*   bsum    = (int*)  carve(1024);
    float* xl      = (float*)carve((size_t)N * 64 * 4);
    float* xr      = (float*)carve((size_t)N * 64 * 4);
    float* h       = (float*)carve((size_t)N * 64 * 4);
    float* ea_csr  = (float*)carve((size_t)(E + 32) * 16 * 4);  // +32 rows pad
    int*   src_csr = (int*)  carve((size_t)(E + 32) * 4);
    (void)ws_size; (void)n_in; (void)out_size;

    const float* Wl1f  = wts + 0;     const float* bl1f = wts + 8192;
    const float* Wr1f  = wts + 8256;  const float* br1f = wts + 16448;
    const float* We1f  = wts + 16512; const float* att1f= wts + 17536;
    const float* b1f   = wts + 17600;
    const float* Wl2f  = wts + 17664; const float* bl2f = wts + 21760;
    const float* Wr2f  = wts + 21824; const float* br2f = wts + 25920;
    const float* We2f  = wts + 25984; const float* att2f= wts + 27008;
    const float* b2f   = wts + 27072;

    hipMemsetAsync(deg, 0, (size_t)N * 4, stream);

    detect_float<<<16, 64, 0, stream>>>(ptrs, in_sizes[0], in_sizes[2], flags);
    detect_idx<<<1, 64, 0, stream>>>(ei, emode);
    convert_weights<<<(WTOTAL + 255) / 256, 256, 0, stream>>>(ptrs, flags, wts);

    count_kernel<<<(E + 255) / 256, 256, 0, stream>>>(ei, deg, emode, E, N);

    int nb = (N + 1023) / 1024;
    scan1<<<nb, 256, 0, stream>>>(deg, rowptr, bsum, N);
    scan2<<<1, 256, 0, stream>>>(bsum, nb);
    scan3<<<(N + 256) / 256, 256, 0, stream>>>(rowptr, fill, bsum, N);

    // scatter + ea permute fused (no intermediate edges array / ea_gather)
    scatter_kernel<<<(E + 255) / 256, 256, 0, stream>>>(
        ei, fill, ea, ea_csr, src_csr, emode, E, N);

    // Layer 1
    dim3 g1((N + 15) / 16, 2);
    node_gemm<128><<<g1, 256, 0, stream>>>(x, Wl1f, bl1f, xl, Wr1f, br1f, xr, N);
    int ng = (N + 3) / 4;
    edge_kernel<8, false><<<ng, 256, 0, stream>>>(
        rowptr, src_csr, ea_csr, xl, xr, We1f, att1f, b1f, h, N);

    // Layer 2
    node_gemm<64><<<g1, 256, 0, stream>>>(h, Wl2f, bl2f, xl, Wr2f, br2f, xr, N);
    edge_kernel<64, true><<<ng, 256, 0, stream>>>(
        rowptr, src_csr, ea_csr, xl, xr, We2f, att2f, b2f, (float*)d_out, N);
}